// Round 1
// baseline (36.477 us; speedup 1.0000x reference)
//
#include <hip/hip_runtime.h>
#include <math.h>

static constexpr int GD  = 8;     // GAUGE_DIM
static constexpr int DG  = 28;    // dim of so(8)
static constexpr int NSEQ = 512;  // N
static constexpr int BN_TOT = 1024; // B*N
static constexpr float EPSF = 1e-8f;

__host__ __device__ constexpr int gidx(int a, int b) {  // a < b
    return a * 7 - a * (a - 1) / 2 + (b - a - 1);
}

// ---------------- Kernel 1: per-(b,n) precompute -----------------
// rcp[n,k] = 1/(sigma+eps); logdet[n] = sum_k log(sigma+eps);
// cterm[n] = -entropy + 0.1*kl_prior   (ALPHA=1, GAMMA=0.1 folded)
__global__ void prep_kernel(const float* __restrict__ mu,
                            const float* __restrict__ sigma,
                            float* __restrict__ rcp,
                            float* __restrict__ logdet,
                            float* __restrict__ cterm) {
    int n = blockIdx.x * blockDim.x + threadIdx.x;
    if (n >= BN_TOT) return;
    float ld = 0.f, ssum = 0.f, msum = 0.f;
#pragma unroll
    for (int k = 0; k < GD; ++k) {
        float s = sigma[(size_t)n * GD + k];
        float m = mu[(size_t)n * GD + k];
        float sp = s + EPSF;
        ld += logf(sp);
        rcp[(size_t)n * GD + k] = 1.0f / sp;
        ssum += s;
        msum += m * m;
    }
    logdet[n] = ld;
    // entropy = 0.5*(K*log(2*pi*e) + logdet); K*log(2pi e) = 22.703016531274763
    float entropy = 0.5f * (22.70301653127476f + ld);
    float klp = 0.5f * (ssum + msum - 8.0f - ld);
    cterm[n] = -entropy + 0.1f * klp;
}

// ---------------- Kernel 2: pair loop, one block per (b,i) -------
__global__ __launch_bounds__(256) void pair_kernel(
    const float* __restrict__ mu, const float* __restrict__ sigma,
    const float* __restrict__ phi, const float* __restrict__ rcp,
    const float* __restrict__ logdet, const float* __restrict__ cterm,
    float* __restrict__ partial) {
    const int bid  = blockIdx.x;          // b*512 + i
    const int base = (bid >> 9) << 9;     // b*512
    const int tid  = threadIdx.x;

    __shared__ float sh_fi[DG];
    __shared__ float sh_mui[GD];
    __shared__ float sh_sigi[GD];
    __shared__ float sh_ld;
    __shared__ float sh_min[4];
    __shared__ float sh_s0[4];
    __shared__ float sh_s1[4];

    if (tid < DG) sh_fi[tid] = phi[(size_t)bid * DG + tid];
    if (tid < GD) {
        sh_mui[tid]  = mu[(size_t)bid * GD + tid];
        sh_sigi[tid] = sigma[(size_t)bid * GD + tid];
    }
    if (tid == 0) sh_ld = logdet[bid];
    __syncthreads();

    // copy row-i state to registers (avoid LDS reads in the hot unroll)
    float fi[DG], mui[GD], sigi[GD];
#pragma unroll
    for (int c = 0; c < DG; ++c) fi[c] = sh_fi[c];
#pragma unroll
    for (int k = 0; k < GD; ++k) { mui[k] = sh_mui[k]; sigi[k] = sh_sigi[k]; }
    const float ld_i = sh_ld;

    float klv[2];

#pragma unroll 1
    for (int jj = 0; jj < 2; ++jj) {
        const int j  = tid + (jj << 8);
        const int gj = base + j;

        float pj[DG];
        {
            const float4* p4 = reinterpret_cast<const float4*>(phi + (size_t)gj * DG);
#pragma unroll
            for (int t = 0; t < 7; ++t) {
                float4 v = p4[t];
                pj[4*t] = v.x; pj[4*t+1] = v.y; pj[4*t+2] = v.z; pj[4*t+3] = v.w;
            }
        }
        float muj[GD], rcj[GD];
        {
            const float4* p4 = reinterpret_cast<const float4*>(mu + (size_t)gj * GD);
            float4 v0 = p4[0], v1 = p4[1];
            muj[0]=v0.x; muj[1]=v0.y; muj[2]=v0.z; muj[3]=v0.w;
            muj[4]=v1.x; muj[5]=v1.y; muj[6]=v1.z; muj[7]=v1.w;
        }
        {
            const float4* p4 = reinterpret_cast<const float4*>(rcp + (size_t)gj * GD);
            float4 v0 = p4[0], v1 = p4[1];
            rcj[0]=v0.x; rcj[1]=v0.y; rcj[2]=v0.z; rcj[3]=v0.w;
            rcj[4]=v1.x; rcj[5]=v1.y; rcj[6]=v1.z; rcj[7]=v1.w;
        }
        const float ld_j = logdet[gj];

        // antisymmetric matrix elements from flat so(8) coords (compile-time folded)
#define MI(r_, c_) ((r_) == (c_) ? 0.0f : ((r_) < (c_) ? fi[gidx((r_),(c_))] : -fi[gidx((c_),(r_))]))
#define MJ(r_, c_) ((r_) == (c_) ? 0.0f : ((r_) < (c_) ? pj[gidx((r_),(c_))] : -pj[gidx((c_),(r_))]))

        // delta_c = fi_c - pj_c + 0.5*[M_i,M_j][p][q]   (== phi_ij of reference)
        float d[DG];
#pragma unroll
        for (int p = 0; p < GD; ++p) {
#pragma unroll
            for (int q = p + 1; q < GD; ++q) {
                float c = 0.0f;
#pragma unroll
                for (int k = 0; k < GD; ++k) {
                    if (k == p || k == q) continue;
                    c += MI(p, k) * MJ(k, q) - MJ(p, k) * MI(k, q);
                }
                d[gidx(p, q)] = fi[gidx(p, q)] - pj[gidx(p, q)] + 0.5f * c;
            }
        }

        // A[p][q] of phi_ij (antisymmetric), used only through matvec
#define AD(p_, q_) ((p_) < (q_) ? d[gidx((p_),(q_))] : -d[gidx((q_),(p_))])

        // r = (I + A + A^2/2! + ... + A^5/5!) mu_j  via Horner
        float r[GD], t[GD];
#pragma unroll
        for (int k = 0; k < GD; ++k) r[k] = muj[k];
#pragma unroll
        for (int s = 5; s >= 1; --s) {
            const float inv = 1.0f / (float)s;
#pragma unroll
            for (int p = 0; p < GD; ++p) {
                float a = 0.0f;
#pragma unroll
                for (int q = 0; q < GD; ++q) {
                    if (q == p) continue;
                    a += AD(p, q) * r[q];
                }
                t[p] = a;
            }
#pragma unroll
            for (int p = 0; p < GD; ++p) r[p] = muj[p] + t[p] * inv;
        }

        // kl = 0.5*( sum_k (sig_i + diff^2)*rcp_j - 8 + ld_j - ld_i )
        float acc = 0.0f;
#pragma unroll
        for (int k = 0; k < GD; ++k) {
            const float df = r[k] - mui[k];
            acc += (sigi[k] + df * df) * rcj[k];
        }
        klv[jj] = 0.5f * (acc - 8.0f + ld_j - ld_i);
#undef MI
#undef MJ
#undef AD
    }

    // ---- block softmax over 512 kl values ----
    const int wave = tid >> 6;
    float m = fminf(klv[0], klv[1]);
#pragma unroll
    for (int off = 32; off > 0; off >>= 1) m = fminf(m, __shfl_xor(m, off));
    if ((tid & 63) == 0) sh_min[wave] = m;
    __syncthreads();
    m = fminf(fminf(sh_min[0], sh_min[1]), fminf(sh_min[2], sh_min[3]));

    float e0 = expf(m - klv[0]);
    float e1 = expf(m - klv[1]);
    float s0 = e0 + e1;
    float s1 = klv[0] * e0 + klv[1] * e1;
#pragma unroll
    for (int off = 32; off > 0; off >>= 1) {
        s0 += __shfl_xor(s0, off);
        s1 += __shfl_xor(s1, off);
    }
    if ((tid & 63) == 0) { sh_s0[wave] = s0; sh_s1[wave] = s1; }
    __syncthreads();
    if (tid == 0) {
        float S0 = sh_s0[0] + sh_s0[1] + sh_s0[2] + sh_s0[3];
        float S1 = sh_s1[0] + sh_s1[1] + sh_s1[2] + sh_s1[3];
        partial[bid] = cterm[bid] + S1 / S0;   // BETA=1
    }
}

// ---------------- Kernel 3: deterministic final reduce -----------
__global__ void reduce_kernel(const float* __restrict__ partial,
                              float* __restrict__ out) {
    __shared__ float sh[4];
    int tid = threadIdx.x;
    float s = 0.f;
    for (int i = tid; i < BN_TOT; i += 256) s += partial[i];
#pragma unroll
    for (int off = 32; off > 0; off >>= 1) s += __shfl_xor(s, off);
    if ((tid & 63) == 0) sh[tid >> 6] = s;
    __syncthreads();
    if (tid == 0)
        out[0] = (sh[0] + sh[1] + sh[2] + sh[3]) * (1.0f / (float)BN_TOT);
}

extern "C" void kernel_launch(void* const* d_in, const int* in_sizes, int n_in,
                              void* d_out, int out_size, void* d_ws, size_t ws_size,
                              hipStream_t stream) {
    const float* mu    = (const float*)d_in[0];
    const float* sigma = (const float*)d_in[1];
    const float* phi   = (const float*)d_in[2];
    float* out = (float*)d_out;
    float* ws  = (float*)d_ws;

    float* rcp     = ws;            // 8192 floats
    float* logdet  = ws + 8192;     // 1024
    float* cterm   = ws + 9216;     // 1024
    float* partial = ws + 10240;    // 1024

    prep_kernel<<<(BN_TOT + 255) / 256, 256, 0, stream>>>(mu, sigma, rcp, logdet, cterm);
    pair_kernel<<<BN_TOT, 256, 0, stream>>>(mu, sigma, phi, rcp, logdet, cterm, partial);
    reduce_kernel<<<1, 256, 0, stream>>>(partial, out);
}

// Round 2
// 23.471 us; speedup vs baseline: 1.5541x; 1.5541x over previous
//
#include <hip/hip_runtime.h>
#include <math.h>

static constexpr int GD  = 8;       // GAUGE_DIM
static constexpr int DG  = 28;      // dim of so(8)
static constexpr int BN_TOT = 1024; // B*N
static constexpr float EPSF = 1e-8f;

__host__ __device__ constexpr int gidx(int a, int b) {  // a < b
    return a * 7 - a * (a - 1) / 2 + (b - a - 1);
}

// force a block-uniform value into an SGPR
__device__ __forceinline__ float rfl(float x) {
    return __int_as_float(__builtin_amdgcn_readfirstlane(__float_as_int(x)));
}

// ---------------- Kernel 1: per-(b,n) precompute -----------------
__global__ void prep_kernel(const float* __restrict__ mu,
                            const float* __restrict__ sigma,
                            float* __restrict__ rcp,
                            float* __restrict__ logdet,
                            float* __restrict__ cterm) {
    int n = blockIdx.x * blockDim.x + threadIdx.x;
    if (n >= BN_TOT) return;
    float ld = 0.f, ssum = 0.f, msum = 0.f;
#pragma unroll
    for (int k = 0; k < GD; ++k) {
        float s = sigma[(size_t)n * GD + k];
        float m = mu[(size_t)n * GD + k];
        float sp = s + EPSF;
        ld += logf(sp);
        rcp[(size_t)n * GD + k] = 1.0f / sp;
        ssum += s;
        msum += m * m;
    }
    logdet[n] = ld;
    float entropy = 0.5f * (22.70301653127476f + ld);   // K*log(2*pi*e)=22.7030...
    float klp = 0.5f * (ssum + msum - 8.0f - ld);
    cterm[n] = -entropy + 0.1f * klp;
}

// ---------------- Kernel 2: pair loop, one block per (b,i), 1 j/thread ----
__global__ __launch_bounds__(512, 4) void pair_kernel(
    const float* __restrict__ mu, const float* __restrict__ sigma,
    const float* __restrict__ phi, const float* __restrict__ rcp,
    const float* __restrict__ logdet, const float* __restrict__ cterm,
    float* __restrict__ partial) {
    const int bid  = blockIdx.x;          // b*512 + i
    const int base = bid & ~511;          // b*512
    const int tid  = threadIdx.x;
    const int gj   = base + tid;

    // ---- block-uniform row-i state -> SGPRs (uniform loads + readfirstlane)
    float fi[DG], mui[GD], sigi[GD];
#pragma unroll
    for (int c = 0; c < DG; ++c) fi[c] = rfl(phi[(size_t)bid * DG + c]);
#pragma unroll
    for (int k = 0; k < GD; ++k) {
        mui[k]  = rfl(mu[(size_t)bid * GD + k]);
        sigi[k] = rfl(sigma[(size_t)bid * GD + k]);
    }
    const float ld_i = rfl(logdet[bid]);

    // ---- per-thread j loads (issue all upfront) ----
    float pj[DG];
    {
        const float4* p4 = reinterpret_cast<const float4*>(phi + (size_t)gj * DG);
#pragma unroll
        for (int t = 0; t < 7; ++t) {
            float4 v = p4[t];
            pj[4*t] = v.x; pj[4*t+1] = v.y; pj[4*t+2] = v.z; pj[4*t+3] = v.w;
        }
    }
    float muj[GD], rcj[GD];
    {
        const float4* p4 = reinterpret_cast<const float4*>(mu + (size_t)gj * GD);
        float4 v0 = p4[0], v1 = p4[1];
        muj[0]=v0.x; muj[1]=v0.y; muj[2]=v0.z; muj[3]=v0.w;
        muj[4]=v1.x; muj[5]=v1.y; muj[6]=v1.z; muj[7]=v1.w;
    }
    {
        const float4* p4 = reinterpret_cast<const float4*>(rcp + (size_t)gj * GD);
        float4 v0 = p4[0], v1 = p4[1];
        rcj[0]=v0.x; rcj[1]=v0.y; rcj[2]=v0.z; rcj[3]=v0.w;
        rcj[4]=v1.x; rcj[5]=v1.y; rcj[6]=v1.z; rcj[7]=v1.w;
    }
    const float ld_j = logdet[gj];

#define MI(r_, c_) ((r_) == (c_) ? 0.0f : ((r_) < (c_) ? fi[gidx((r_),(c_))] : -fi[gidx((c_),(r_))]))
#define MJ(r_, c_) ((r_) == (c_) ? 0.0f : ((r_) < (c_) ? pj[gidx((r_),(c_))] : -pj[gidx((c_),(r_))]))

    // delta_c = fi_c - pj_c + 0.5*[M_i,M_j][p][q]  (== phi_ij of reference)
    float d[DG];
#pragma unroll
    for (int p = 0; p < GD; ++p) {
#pragma unroll
        for (int q = p + 1; q < GD; ++q) {
            float c = 0.0f;
#pragma unroll
            for (int k = 0; k < GD; ++k) {
                if (k == p || k == q) continue;
                c += MI(p, k) * MJ(k, q) - MJ(p, k) * MI(k, q);
            }
            d[gidx(p, q)] = fi[gidx(p, q)] - pj[gidx(p, q)] + 0.5f * c;
        }
    }

#define AD(p_, q_) ((p_) < (q_) ? d[gidx((p_),(q_))] : -d[gidx((q_),(p_))])

    // r = (I + A + A^2/2! + ... + A^5/5!) mu_j  via Horner
    float r[GD], t[GD];
#pragma unroll
    for (int k = 0; k < GD; ++k) r[k] = muj[k];
#pragma unroll
    for (int s = 5; s >= 1; --s) {
        const float inv = 1.0f / (float)s;
#pragma unroll
        for (int p = 0; p < GD; ++p) {
            float a = 0.0f;
#pragma unroll
            for (int q = 0; q < GD; ++q) {
                if (q == p) continue;
                a += AD(p, q) * r[q];
            }
            t[p] = a;
        }
#pragma unroll
        for (int p = 0; p < GD; ++p) r[p] = muj[p] + t[p] * inv;
    }

    // kl = 0.5*( sum_k (sig_i + diff^2)*rcp_j - 8 + ld_j - ld_i )
    float acc = 0.0f;
#pragma unroll
    for (int k = 0; k < GD; ++k) {
        const float df = r[k] - mui[k];
        acc += (sigi[k] + df * df) * rcj[k];
    }
    const float klv = 0.5f * (acc - 8.0f + ld_j - ld_i);
#undef MI
#undef MJ
#undef AD

    // ---- block softmax over 512 kl values (8 waves) ----
    __shared__ float sh_min[8];
    __shared__ float sh_s0[8];
    __shared__ float sh_s1[8];
    const int wave = tid >> 6;

    float m = klv;
#pragma unroll
    for (int off = 32; off > 0; off >>= 1) m = fminf(m, __shfl_xor(m, off));
    if ((tid & 63) == 0) sh_min[wave] = m;
    __syncthreads();
#pragma unroll
    for (int w = 0; w < 8; ++w) m = fminf(m, sh_min[w]);

    float e  = expf(m - klv);
    float s0 = e;
    float s1 = klv * e;
#pragma unroll
    for (int off = 32; off > 0; off >>= 1) {
        s0 += __shfl_xor(s0, off);
        s1 += __shfl_xor(s1, off);
    }
    if ((tid & 63) == 0) { sh_s0[wave] = s0; sh_s1[wave] = s1; }
    __syncthreads();
    if (tid == 0) {
        float S0 = 0.f, S1 = 0.f;
#pragma unroll
        for (int w = 0; w < 8; ++w) { S0 += sh_s0[w]; S1 += sh_s1[w]; }
        partial[bid] = cterm[bid] + S1 / S0;   // BETA=1
    }
}

// ---------------- Kernel 3: deterministic final reduce -----------
__global__ void reduce_kernel(const float* __restrict__ partial,
                              float* __restrict__ out) {
    __shared__ float sh[4];
    int tid = threadIdx.x;
    float s = 0.f;
    for (int i = tid; i < BN_TOT; i += 256) s += partial[i];
#pragma unroll
    for (int off = 32; off > 0; off >>= 1) s += __shfl_xor(s, off);
    if ((tid & 63) == 0) sh[tid >> 6] = s;
    __syncthreads();
    if (tid == 0)
        out[0] = (sh[0] + sh[1] + sh[2] + sh[3]) * (1.0f / (float)BN_TOT);
}

extern "C" void kernel_launch(void* const* d_in, const int* in_sizes, int n_in,
                              void* d_out, int out_size, void* d_ws, size_t ws_size,
                              hipStream_t stream) {
    const float* mu    = (const float*)d_in[0];
    const float* sigma = (const float*)d_in[1];
    const float* phi   = (const float*)d_in[2];
    float* out = (float*)d_out;
    float* ws  = (float*)d_ws;

    float* rcp     = ws;            // 8192 floats
    float* logdet  = ws + 8192;     // 1024
    float* cterm   = ws + 9216;     // 1024
    float* partial = ws + 10240;    // 1024

    prep_kernel<<<(BN_TOT + 255) / 256, 256, 0, stream>>>(mu, sigma, rcp, logdet, cterm);
    pair_kernel<<<BN_TOT, 512, 0, stream>>>(mu, sigma, phi, rcp, logdet, cterm, partial);
    reduce_kernel<<<1, 256, 0, stream>>>(partial, out);
}

// Round 4
// 22.804 us; speedup vs baseline: 1.5996x; 1.0293x over previous
//
#include <hip/hip_runtime.h>
#include <math.h>

static constexpr int GD  = 8;       // GAUGE_DIM
static constexpr int DG  = 28;      // dim of so(8)
static constexpr int BN_TOT = 1024; // B*N
static constexpr float EPSF = 1e-8f;

__host__ __device__ constexpr int gidx(int a, int b) {  // a < b
    return a * 7 - a * (a - 1) / 2 + (b - a - 1);
}

// force a block-uniform value into an SGPR
__device__ __forceinline__ float rfl(float x) {
    return __int_as_float(__builtin_amdgcn_readfirstlane(__float_as_int(x)));
}

// ---- Kernel 1: fused prep + pair + block softmax; one block per (b,i) ----
__global__ __launch_bounds__(512, 4) void vfe_kernel(
    const float* __restrict__ mu, const float* __restrict__ sigma,
    const float* __restrict__ phi,
    float* __restrict__ partial) {
    const int bid     = blockIdx.x;     // b*512 + i
    const int base    = bid & ~511;     // b*512
    const int tid     = threadIdx.x;
    const int gj      = base + tid;
    const int i_local = bid & 511;

    __shared__ float sh_min[8];
    __shared__ float sh_s0[8];
    __shared__ float sh_s1[8];
    __shared__ float sh_ldi;

    // ---- per-thread j loads first (longest latency) ----
    float pj[DG];
    {
        const float4* p4 = reinterpret_cast<const float4*>(phi + (size_t)gj * DG);
#pragma unroll
        for (int t = 0; t < 7; ++t) {
            float4 v = p4[t];
            pj[4*t] = v.x; pj[4*t+1] = v.y; pj[4*t+2] = v.z; pj[4*t+3] = v.w;
        }
    }
    float muj[GD], sgj[GD];
    {
        const float4* p4 = reinterpret_cast<const float4*>(mu + (size_t)gj * GD);
        float4 v0 = p4[0], v1 = p4[1];
        muj[0]=v0.x; muj[1]=v0.y; muj[2]=v0.z; muj[3]=v0.w;
        muj[4]=v1.x; muj[5]=v1.y; muj[6]=v1.z; muj[7]=v1.w;
    }
    {
        const float4* p4 = reinterpret_cast<const float4*>(sigma + (size_t)gj * GD);
        float4 v0 = p4[0], v1 = p4[1];
        sgj[0]=v0.x; sgj[1]=v0.y; sgj[2]=v0.z; sgj[3]=v0.w;
        sgj[4]=v1.x; sgj[5]=v1.y; sgj[6]=v1.z; sgj[7]=v1.w;
    }

    // ---- block-uniform row-i state -> SGPRs (vector loads + readfirstlane) ----
    float fi[DG], mui[GD], sigi[GD];
    {
        const float4* p4 = reinterpret_cast<const float4*>(phi + (size_t)bid * DG);
#pragma unroll
        for (int t = 0; t < 7; ++t) {
            float4 v = p4[t];
            fi[4*t]   = rfl(v.x); fi[4*t+1] = rfl(v.y);
            fi[4*t+2] = rfl(v.z); fi[4*t+3] = rfl(v.w);
        }
    }
    {
        const float4* p4 = reinterpret_cast<const float4*>(mu + (size_t)bid * GD);
        float4 v0 = p4[0], v1 = p4[1];
        mui[0]=rfl(v0.x); mui[1]=rfl(v0.y); mui[2]=rfl(v0.z); mui[3]=rfl(v0.w);
        mui[4]=rfl(v1.x); mui[5]=rfl(v1.y); mui[6]=rfl(v1.z); mui[7]=rfl(v1.w);
    }
    {
        const float4* p4 = reinterpret_cast<const float4*>(sigma + (size_t)bid * GD);
        float4 v0 = p4[0], v1 = p4[1];
        sigi[0]=rfl(v0.x); sigi[1]=rfl(v0.y); sigi[2]=rfl(v0.z); sigi[3]=rfl(v0.w);
        sigi[4]=rfl(v1.x); sigi[5]=rfl(v1.y); sigi[6]=rfl(v1.z); sigi[7]=rfl(v1.w);
    }

    // ---- per-thread j-side precompute: rcp(sigma_j+eps), logdet_j ----
    float rcj[GD];
    float ldj = 0.0f;
#pragma unroll
    for (int k = 0; k < GD; ++k) {
        const float sp = sgj[k] + EPSF;
        rcj[k] = __builtin_amdgcn_rcpf(sp);
        ldj += __logf(sp);
    }
    // thread with tid == i has ld_j == ld_i: publish (read by tid0 after barriers)
    if (tid == i_local) sh_ldi = ldj;

#define MI(r_, c_) ((r_) == (c_) ? 0.0f : ((r_) < (c_) ? fi[gidx((r_),(c_))] : -fi[gidx((c_),(r_))]))
#define MJ(r_, c_) ((r_) == (c_) ? 0.0f : ((r_) < (c_) ? pj[gidx((r_),(c_))] : -pj[gidx((c_),(r_))]))

    // delta_c = fi_c - pj_c + 0.5*[M_i,M_j][p][q]  (== phi_ij of reference)
    float d[DG];
#pragma unroll
    for (int p = 0; p < GD; ++p) {
#pragma unroll
        for (int q = p + 1; q < GD; ++q) {
            float c = 0.0f;
#pragma unroll
            for (int k = 0; k < GD; ++k) {
                if (k == p || k == q) continue;
                c += MI(p, k) * MJ(k, q) - MJ(p, k) * MI(k, q);
            }
            d[gidx(p, q)] = fi[gidx(p, q)] - pj[gidx(p, q)] + 0.5f * c;
        }
    }

#define AD(p_, q_) ((p_) < (q_) ? d[gidx((p_),(q_))] : -d[gidx((q_),(p_))])

    // r = (I + A + A^2/2! + ... + A^5/5!) mu_j  via Horner
    float r[GD], t[GD];
#pragma unroll
    for (int k = 0; k < GD; ++k) r[k] = muj[k];
#pragma unroll
    for (int s = 5; s >= 1; --s) {
        const float inv = 1.0f / (float)s;
#pragma unroll
        for (int p = 0; p < GD; ++p) {
            float a = 0.0f;
#pragma unroll
            for (int q = 0; q < GD; ++q) {
                if (q == p) continue;
                a += AD(p, q) * r[q];
            }
            t[p] = a;
        }
#pragma unroll
        for (int p = 0; p < GD; ++p) r[p] = muj[p] + t[p] * inv;
    }

    // kl_base = kl + 0.5*ld_i  (uniform shift; softmax weights shift-invariant)
    float acc = 0.0f;
#pragma unroll
    for (int k = 0; k < GD; ++k) {
        const float df = r[k] - mui[k];
        acc += (sigi[k] + df * df) * rcj[k];
    }
    const float klb = 0.5f * (acc - 8.0f + ldj);
#undef MI
#undef MJ
#undef AD

    // ---- block softmax over 512 kl values (8 waves) ----
    const int wave = tid >> 6;
    float m = klb;
#pragma unroll
    for (int off = 32; off > 0; off >>= 1) m = fminf(m, __shfl_xor(m, off));
    if ((tid & 63) == 0) sh_min[wave] = m;
    __syncthreads();
#pragma unroll
    for (int w = 0; w < 8; ++w) m = fminf(m, sh_min[w]);

    const float e  = __expf(m - klb);
    float s0 = e;
    float s1 = klb * e;
#pragma unroll
    for (int off = 32; off > 0; off >>= 1) {
        s0 += __shfl_xor(s0, off);
        s1 += __shfl_xor(s1, off);
    }
    if ((tid & 63) == 0) { sh_s0[wave] = s0; sh_s1[wave] = s1; }
    __syncthreads();
    if (tid == 0) {
        float S0 = 0.f, S1 = 0.f;
#pragma unroll
        for (int w = 0; w < 8; ++w) { S0 += sh_s0[w]; S1 += sh_s1[w]; }
        const float ld_i    = sh_ldi;
        const float f_align = S1 / S0 - 0.5f * ld_i;
        float ssum = 0.f, msum = 0.f;
#pragma unroll
        for (int k = 0; k < GD; ++k) { ssum += sigi[k]; msum += mui[k] * mui[k]; }
        // -entropy + 0.1*kl_prior ; K*log(2*pi*e) = 22.703016531274763
        const float cterm = -0.5f * (22.70301653127476f + ld_i)
                          + 0.05f * (ssum + msum - 8.0f - ld_i);
        partial[bid] = cterm + f_align;
    }
}

// ---- Kernel 2: deterministic final reduce (kernel boundary = visibility) ----
__global__ __launch_bounds__(512) void reduce_kernel(
    const float* __restrict__ partial, float* __restrict__ out) {
    __shared__ float sh[8];
    const int tid = threadIdx.x;
    float s = partial[tid] + partial[tid + 512];
#pragma unroll
    for (int off = 32; off > 0; off >>= 1) s += __shfl_xor(s, off);
    if ((tid & 63) == 0) sh[tid >> 6] = s;
    __syncthreads();
    if (tid == 0) {
        float tot = 0.f;
#pragma unroll
        for (int w = 0; w < 8; ++w) tot += sh[w];
        out[0] = tot * (1.0f / (float)BN_TOT);
    }
}

extern "C" void kernel_launch(void* const* d_in, const int* in_sizes, int n_in,
                              void* d_out, int out_size, void* d_ws, size_t ws_size,
                              hipStream_t stream) {
    const float* mu    = (const float*)d_in[0];
    const float* sigma = (const float*)d_in[1];
    const float* phi   = (const float*)d_in[2];
    float* out = (float*)d_out;
    float* ws  = (float*)d_ws;

    float* partial = ws;   // 1024 floats

    vfe_kernel<<<BN_TOT, 512, 0, stream>>>(mu, sigma, phi, partial);
    reduce_kernel<<<1, 512, 0, stream>>>(partial, out);
}

// Round 5
// 22.080 us; speedup vs baseline: 1.6521x; 1.0328x over previous
//
#include <hip/hip_runtime.h>
#include <math.h>

static constexpr int GD  = 8;       // GAUGE_DIM
static constexpr int DG  = 28;      // dim of so(8)
static constexpr int BN_TOT = 1024; // B*N
static constexpr float EPSF = 1e-8f;

__host__ __device__ constexpr int gidx(int a, int b) {  // a < b
    return a * 7 - a * (a - 1) / 2 + (b - a - 1);
}

// force a block-uniform value into an SGPR
__device__ __forceinline__ float rfl(float x) {
    return __int_as_float(__builtin_amdgcn_readfirstlane(__float_as_int(x)));
}

// ---- Kernel 1: one block per (row i, j-half); 256 threads, 1 j/thread ----
// Writes per-block online-softmax triple (m, s0, s1) over its 256 kl values.
__global__ __launch_bounds__(256, 5) void vfe_kernel(
    const float* __restrict__ mu, const float* __restrict__ sigma,
    const float* __restrict__ phi,
    float* __restrict__ m_arr, float* __restrict__ s0_arr,
    float* __restrict__ s1_arr) {
    const int bid  = blockIdx.x;        // 2*i + half
    const int row  = bid >> 1;          // global i in [0,1024)
    const int half = bid & 1;
    const int base = row & ~511;        // b*512
    const int tid  = threadIdx.x;
    const int gj   = base + (half << 8) + tid;

    __shared__ float sh_min[4];
    __shared__ float sh_s0[4];
    __shared__ float sh_s1[4];

    // ---- per-thread j loads first (longest latency) ----
    float pj[DG];
    {
        const float4* p4 = reinterpret_cast<const float4*>(phi + (size_t)gj * DG);
#pragma unroll
        for (int t = 0; t < 7; ++t) {
            float4 v = p4[t];
            pj[4*t] = v.x; pj[4*t+1] = v.y; pj[4*t+2] = v.z; pj[4*t+3] = v.w;
        }
    }
    float muj[GD], rcj[GD];
    float ldj = 0.0f;
    {
        const float4* p4 = reinterpret_cast<const float4*>(mu + (size_t)gj * GD);
        float4 v0 = p4[0], v1 = p4[1];
        muj[0]=v0.x; muj[1]=v0.y; muj[2]=v0.z; muj[3]=v0.w;
        muj[4]=v1.x; muj[5]=v1.y; muj[6]=v1.z; muj[7]=v1.w;
    }
    {
        const float4* p4 = reinterpret_cast<const float4*>(sigma + (size_t)gj * GD);
        float4 v0 = p4[0], v1 = p4[1];
        float s[GD] = {v0.x, v0.y, v0.z, v0.w, v1.x, v1.y, v1.z, v1.w};
#pragma unroll
        for (int k = 0; k < GD; ++k) {
            const float sp = s[k] + EPSF;
            rcj[k] = __builtin_amdgcn_rcpf(sp);
            ldj += __logf(sp);
        }
    }

    // ---- block-uniform row-i state -> SGPRs ----
    float fi[DG], mui[GD], sigi[GD];
    {
        const float4* p4 = reinterpret_cast<const float4*>(phi + (size_t)row * DG);
#pragma unroll
        for (int t = 0; t < 7; ++t) {
            float4 v = p4[t];
            fi[4*t]   = rfl(v.x); fi[4*t+1] = rfl(v.y);
            fi[4*t+2] = rfl(v.z); fi[4*t+3] = rfl(v.w);
        }
    }
    {
        const float4* p4 = reinterpret_cast<const float4*>(mu + (size_t)row * GD);
        float4 v0 = p4[0], v1 = p4[1];
        mui[0]=rfl(v0.x); mui[1]=rfl(v0.y); mui[2]=rfl(v0.z); mui[3]=rfl(v0.w);
        mui[4]=rfl(v1.x); mui[5]=rfl(v1.y); mui[6]=rfl(v1.z); mui[7]=rfl(v1.w);
    }
    {
        const float4* p4 = reinterpret_cast<const float4*>(sigma + (size_t)row * GD);
        float4 v0 = p4[0], v1 = p4[1];
        sigi[0]=rfl(v0.x); sigi[1]=rfl(v0.y); sigi[2]=rfl(v0.z); sigi[3]=rfl(v0.w);
        sigi[4]=rfl(v1.x); sigi[5]=rfl(v1.y); sigi[6]=rfl(v1.z); sigi[7]=rfl(v1.w);
    }

#define MI(r_, c_) ((r_) == (c_) ? 0.0f : ((r_) < (c_) ? fi[gidx((r_),(c_))] : -fi[gidx((c_),(r_))]))
#define MJ(r_, c_) ((r_) == (c_) ? 0.0f : ((r_) < (c_) ? pj[gidx((r_),(c_))] : -pj[gidx((c_),(r_))]))

    // delta_c = fi_c - pj_c + 0.5*[M_i,M_j][p][q]  (== phi_ij of reference)
    float d[DG];
#pragma unroll
    for (int p = 0; p < GD; ++p) {
#pragma unroll
        for (int q = p + 1; q < GD; ++q) {
            float c = 0.0f;
#pragma unroll
            for (int k = 0; k < GD; ++k) {
                if (k == p || k == q) continue;
                c += MI(p, k) * MJ(k, q) - MJ(p, k) * MI(k, q);
            }
            d[gidx(p, q)] = fi[gidx(p, q)] - pj[gidx(p, q)] + 0.5f * c;
        }
    }

#define AD(p_, q_) ((p_) < (q_) ? d[gidx((p_),(q_))] : -d[gidx((q_),(p_))])

    // r = (I + A + A^2/2! + ... + A^5/5!) mu_j  via Horner (rolled s-loop)
    float r[GD], t[GD];
#pragma unroll
    for (int k = 0; k < GD; ++k) r[k] = muj[k];
    float sf = 5.0f;
#pragma unroll 1
    for (int s = 0; s < 5; ++s) {
        const float inv = __builtin_amdgcn_rcpf(sf);
#pragma unroll
        for (int p = 0; p < GD; ++p) {
            float a = 0.0f;
#pragma unroll
            for (int q = 0; q < GD; ++q) {
                if (q == p) continue;
                a += AD(p, q) * r[q];
            }
            t[p] = a;
        }
#pragma unroll
        for (int p = 0; p < GD; ++p) r[p] = fmaf(t[p], inv, muj[p]);
        sf -= 1.0f;
    }

    // klb = kl + 0.5*ld_i  (uniform shift; softmax weights shift-invariant;
    // the -0.5*ld_i correction is applied in the reduce kernel)
    float acc = 0.0f;
#pragma unroll
    for (int k = 0; k < GD; ++k) {
        const float df = r[k] - mui[k];
        acc += (sigi[k] + df * df) * rcj[k];
    }
    const float klb = 0.5f * (acc - 8.0f + ldj);
#undef MI
#undef MJ
#undef AD

    // ---- block online-softmax partial over 256 kl values (4 waves) ----
    const int wave = tid >> 6;
    float m = klb;
#pragma unroll
    for (int off = 32; off > 0; off >>= 1) m = fminf(m, __shfl_xor(m, off));
    if ((tid & 63) == 0) sh_min[wave] = m;
    __syncthreads();
    m = fminf(fminf(sh_min[0], sh_min[1]), fminf(sh_min[2], sh_min[3]));

    const float e  = __expf(m - klb);
    float s0 = e;
    float s1 = klb * e;
#pragma unroll
    for (int off = 32; off > 0; off >>= 1) {
        s0 += __shfl_xor(s0, off);
        s1 += __shfl_xor(s1, off);
    }
    if ((tid & 63) == 0) { sh_s0[wave] = s0; sh_s1[wave] = s1; }
    __syncthreads();
    if (tid == 0) {
        m_arr[bid]  = m;
        s0_arr[bid] = sh_s0[0] + sh_s0[1] + sh_s0[2] + sh_s0[3];
        s1_arr[bid] = sh_s1[0] + sh_s1[1] + sh_s1[2] + sh_s1[3];
    }
}

// ---- Kernel 2: merge halves + per-row constants + final sum ----
__global__ __launch_bounds__(1024) void reduce_kernel(
    const float* __restrict__ mu, const float* __restrict__ sigma,
    const float* __restrict__ m_arr, const float* __restrict__ s0_arr,
    const float* __restrict__ s1_arr, float* __restrict__ out) {
    __shared__ float sh[16];
    const int i = threadIdx.x;   // row in [0,1024)

    // merge the two half-softmax triples (exact online-softmax algebra)
    const float mA = m_arr[2*i],  mB = m_arr[2*i+1];
    const float m  = fminf(mA, mB);
    const float cA = __expf(m - mA), cB = __expf(m - mB);
    const float S0 = cA * s0_arr[2*i] + cB * s0_arr[2*i+1];
    const float S1 = cA * s1_arr[2*i] + cB * s1_arr[2*i+1];

    // per-row i-side constants
    float ld = 0.f, ssum = 0.f, msum = 0.f;
#pragma unroll
    for (int k = 0; k < GD; ++k) {
        const float s = sigma[(size_t)i * GD + k];
        const float mm = mu[(size_t)i * GD + k];
        ld += __logf(s + EPSF);
        ssum += s;
        msum += mm * mm;
    }
    const float f_align = S1 / S0 - 0.5f * ld;
    // -entropy + 0.1*kl_prior ; K*log(2*pi*e) = 22.703016531274763
    const float cterm = -0.5f * (22.70301653127476f + ld)
                      + 0.05f * (ssum + msum - 8.0f - ld);
    float v = cterm + f_align;

    // block reduce over 1024 threads (16 waves)
#pragma unroll
    for (int off = 32; off > 0; off >>= 1) v += __shfl_xor(v, off);
    if ((i & 63) == 0) sh[i >> 6] = v;
    __syncthreads();
    if (i == 0) {
        float tot = 0.f;
#pragma unroll
        for (int w = 0; w < 16; ++w) tot += sh[w];
        out[0] = tot * (1.0f / (float)BN_TOT);
    }
}

extern "C" void kernel_launch(void* const* d_in, const int* in_sizes, int n_in,
                              void* d_out, int out_size, void* d_ws, size_t ws_size,
                              hipStream_t stream) {
    const float* mu    = (const float*)d_in[0];
    const float* sigma = (const float*)d_in[1];
    const float* phi   = (const float*)d_in[2];
    float* out = (float*)d_out;
    float* ws  = (float*)d_ws;

    float* m_arr  = ws;          // 2048 floats
    float* s0_arr = ws + 2048;   // 2048
    float* s1_arr = ws + 4096;   // 2048

    vfe_kernel<<<2 * BN_TOT, 256, 0, stream>>>(mu, sigma, phi, m_arr, s0_arr, s1_arr);
    reduce_kernel<<<1, 1024, 0, stream>>>(mu, sigma, m_arr, s0_arr, s1_arr, out);
}